// Round 17
// baseline (98.311 us; speedup 1.0000x reference)
//
#include <hip/hip_runtime.h>
#include <hip/hip_bf16.h>

typedef __bf16 bf16;
typedef __bf16 bf16x4 __attribute__((ext_vector_type(4)));
typedef __bf16 bf16x8 __attribute__((ext_vector_type(8)));
typedef float f32x4 __attribute__((ext_vector_type(4)));

#define NN 1024
#define GH 128
#define MROWS 8192  // 8*1024

static __device__ __forceinline__ f32x4 mfma16(bf16x8 a, bf16x8 b, f32x4 c) {
    return __builtin_amdgcn_mfma_f32_16x16x32_bf16(a, b, c, 0, 0, 0);
}

// ---------------- wtrans0: Wt0[n][k] = (bf16)W0[k][n] (needed before gemm role) ----------------
__global__ __launch_bounds__(256) void wtrans0_kernel(const float* __restrict__ W0,
                                                      bf16* __restrict__ T0) {
    int t = blockIdx.x * 256 + threadIdx.x;  // 0..16383 units of 8
    int n = t & 127, k0 = (t >> 7) * 8;
    bf16x8 o;
#pragma unroll
    for (int ii = 0; ii < 8; ++ii) o[ii] = (bf16)W0[(size_t)(k0 + ii) * GH + n];
    *reinterpret_cast<bf16x8*>(T0 + (size_t)n * NN + k0) = o;
}

// ---------------- merged prep ∥ gemm, INTERLEAVED roles, 32KB LDS ----------------
// gemm role (bid%5==0, 256 blocks): Yt[n][m] = bf16(sum_k aa[m][k]*Wt0[n][k]) (UNSCALED),
//   M=32 tile, A staged per K-half (32KB). XCD-locked: batch(lb)=bid%8.
// prep role (1024 blocks): A01b bitmask (8 rows) + dinv + Wt1-3 (6 units, threads 0..5).
__global__ __launch_bounds__(512, 4) void prep_gemm_kernel(
        const int* __restrict__ rpa, const float* __restrict__ aa,
        const float* __restrict__ W1, const float* __restrict__ W2, const float* __restrict__ W3,
        const bf16* __restrict__ Wt0,
        unsigned char* __restrict__ A01b, float* __restrict__ dinv,
        bf16* __restrict__ T1, bf16* __restrict__ T2, bf16* __restrict__ T3,
        bf16* __restrict__ Yt) {
    __shared__ bf16 Alds[16384];  // 32KB (gemm role only; prep role just reserves it)
    int bid = blockIdx.x, tid = threadIdx.x;
    int wave = tid >> 6, lane = tid & 63;
    if (bid % 5 != 0) {
        // ---- prep role ----
        int j = bid - bid / 5 - 1;           // bijective 0..1023
        int row = j * 8 + wave;              // 8 rows/block, one per wave
        int i = row & (NN - 1);
        const int4* p = reinterpret_cast<const int4*>(rpa + (size_t)row * NN);
        unsigned char* brow = A01b + (size_t)row * 128;
        int cnt = 0;
#pragma unroll
        for (int it = 0; it < 4; ++it) {
            int4 v = p[lane + it * 64];
            int jj = (lane + it * 64) * 4;
            int a0 = (v.x != 0), a1 = (v.y != 0), a2 = (v.z != 0), a3 = (v.w != 0);
            cnt += (a0 & (jj + 0 != i)) + (a1 & (jj + 1 != i)) +
                   (a2 & (jj + 2 != i)) + (a3 & (jj + 3 != i));
            unsigned nib = (unsigned)(a0 | (jj + 0 == i))
                         | ((unsigned)(a1 | (jj + 1 == i)) << 1)
                         | ((unsigned)(a2 | (jj + 2 == i)) << 2)
                         | ((unsigned)(a3 | (jj + 3 == i)) << 3);
            unsigned pn = __shfl_xor(nib, 1, 64);
            if (!(lane & 1))
                brow[it * 32 + (lane >> 1)] = (unsigned char)(nib | (pn << 4));
        }
#pragma unroll
        for (int off = 32; off > 0; off >>= 1) cnt += __shfl_down(cnt, off, 64);
        if (lane == 0) dinv[row] = rsqrtf((float)(cnt + 1));  // +1 self-loop
        if (tid < 6) {
            int t = j * 6 + tid;  // 0..6143 (3 x 2048 units)
            const float* W; bf16* T; int local;
            if (t < 2048)      { W = W1; T = T1; local = t; }
            else if (t < 4096) { W = W2; T = T2; local = t - 2048; }
            else               { W = W3; T = T3; local = t - 4096; }
            int n = local & 127, k0 = (local >> 7) * 8;
            bf16x8 o;
#pragma unroll
            for (int ii = 0; ii < 8; ++ii) o[ii] = (bf16)W[(size_t)(k0 + ii) * GH + n];
            *reinterpret_cast<bf16x8*>(T + (size_t)n * GH + k0) = o;
        }
    } else {
        // ---- gemm role (R14 structure, K-halved staging for 32KB LDS) ----
        int g = bid / 5;                     // 0..255
        int lrow = lane & 15, lg = lane >> 4;
        int lb = (bid & 7) * 32 + (g >> 3);  // bijective; batch(lb) = bid%8 = XCD
        int m0 = lb * 32;
        int c0 = wave * 16;
        const bf16* Bp = Wt0 + (size_t)(c0 + lrow) * NN + lg * 8;
        f32x4 acc[2][2] = {};
        int arow = tid >> 4;                 // staging: row 0..31
        int au   = (tid & 15) * 4;           // 4 units (of 8 f32) per thread per half
        int ars  = arow & 7;
#pragma unroll
        for (int h = 0; h < 2; ++h) {
            if (h) __syncthreads();          // WAR: previous-half A-reads done
            {
                const float* src = aa + (size_t)(m0 + arow) * NN + h * 512 + au * 8;
#pragma unroll
                for (int i = 0; i < 4; ++i) {
                    float4 f0 = *reinterpret_cast<const float4*>(src + i * 8);
                    float4 f1 = *reinterpret_cast<const float4*>(src + i * 8 + 4);
                    bf16x8 v;
                    v[0] = (bf16)f0.x; v[1] = (bf16)f0.y; v[2] = (bf16)f0.z; v[3] = (bf16)f0.w;
                    v[4] = (bf16)f1.x; v[5] = (bf16)f1.y; v[6] = (bf16)f1.z; v[7] = (bf16)f1.w;
                    *reinterpret_cast<bf16x8*>(&Alds[(arow * 64 + ((au + i) ^ ars)) * 8]) = v;
                }
            }
            __syncthreads();
#pragma unroll
            for (int fl = 0; fl < 16; ++fl) {
                int f = h * 16 + fl;
                bf16x8 bb = *reinterpret_cast<const bf16x8*>(Bp + f * 32);
                int ul = fl * 4 + lg;
#pragma unroll
                for (int rg = 0; rg < 2; ++rg) {
                    int r = rg * 16 + lrow;
                    bf16x8 a = *reinterpret_cast<const bf16x8*>(&Alds[(r * 64 + (ul ^ (r & 7))) * 8]);
                    acc[rg][f & 1] = mfma16(a, bb, acc[rg][f & 1]);
                }
            }
        }
        int rl = lg * 4;
        int col = c0 + lrow;
#pragma unroll
        for (int rg = 0; rg < 2; ++rg) {
            f32x4 s = acc[rg][0] + acc[rg][1];
            int rbase = m0 + rg * 16 + rl;
            bf16x4 o;
            o[0] = (bf16)s[0]; o[1] = (bf16)s[1]; o[2] = (bf16)s[2]; o[3] = (bf16)s[3];
            *reinterpret_cast<bf16x4*>(Yt + (size_t)col * MROWS + rbase) = o;
        }
    }
}

// ---------------- fused3 (R14/R16 verified): T = A_b @ Xt_b ; [U=T@W] ; v = relu(D*U+b) ----------------
// DSCALE (layer 1): A entries = bf16(dinv_j) instead of 1.0 (Yt unscaled). R16-verified.
// Dedicated Ths/Tls (R10 race lesson: never alias LDS across MFMA phases).
template <int MODE, bool HASW, bool DSCALE>
__global__ __launch_bounds__(512, 4) void fused3_kernel(const unsigned char* __restrict__ A01b,
                                                        const bf16* __restrict__ Xt,
                                                        const bf16* __restrict__ Wt,
                                                        const float* __restrict__ dinv,
                                                        const float* __restrict__ bias,
                                                        bf16* __restrict__ Hst,
                                                        float* __restrict__ outp) {
    __shared__ bf16 Alds[16384];  // 32KB: [32 rows][64 units] (one K-half)
    __shared__ bf16 Ths[4096];    // 8KB: 32x128 T hi (dedicated)
    __shared__ bf16 Tls[4096];    // 8KB: T lo
    int tid = threadIdx.x;
    int wave = tid >> 6, lane = tid & 63;
    int lrow = lane & 15, lg = lane >> 4;
    int lb = (blockIdx.x & 7) * 32 + (blockIdx.x >> 3);
    int m0 = lb * 32;
    int b = blockIdx.x & 7;
    int c0 = wave * 16;
    const bf16* Bp = Xt + (size_t)(c0 + lrow) * MROWS + b * NN + lg * 8;
    f32x4 acc[2][2] = {};
    int erow = tid >> 4;                 // expansion: thread's row (0..31)
    int eub  = (tid & 15) * 4;           // 4 units (bytes) per thread per half
    int ers  = erow & 7;
#pragma unroll
    for (int h = 0; h < 2; ++h) {
        if (h) __syncthreads();          // WAR: all half-0 A-reads done before overwrite
        {
            unsigned w = *reinterpret_cast<const unsigned*>(
                A01b + (size_t)(m0 + erow) * 128 + h * 64 + eub);
#pragma unroll
            for (int i = 0; i < 4; ++i) {
                unsigned byte = (w >> (8 * i)) & 0xffu;
                bf16x8 v;
                if constexpr (DSCALE) {
                    const float* dq = dinv + b * NN + (h * 64 + eub + i) * 8;
                    float4 q0 = *reinterpret_cast<const float4*>(dq);
                    float4 q1 = *reinterpret_cast<const float4*>(dq + 4);
                    v[0] = (byte & 1u)   ? (bf16)q0.x : (bf16)0.f;
                    v[1] = (byte & 2u)   ? (bf16)q0.y : (bf16)0.f;
                    v[2] = (byte & 4u)   ? (bf16)q0.z : (bf16)0.f;
                    v[3] = (byte & 8u)   ? (bf16)q0.w : (bf16)0.f;
                    v[4] = (byte & 16u)  ? (bf16)q1.x : (bf16)0.f;
                    v[5] = (byte & 32u)  ? (bf16)q1.y : (bf16)0.f;
                    v[6] = (byte & 64u)  ? (bf16)q1.z : (bf16)0.f;
                    v[7] = (byte & 128u) ? (bf16)q1.w : (bf16)0.f;
                } else {
#pragma unroll
                    for (int k = 0; k < 8; ++k) v[k] = ((byte >> k) & 1u) ? (bf16)1.f : (bf16)0.f;
                }
                *reinterpret_cast<bf16x8*>(&Alds[(erow * 64 + ((eub + i) ^ ers)) * 8]) = v;
            }
        }
        __syncthreads();
#pragma unroll
        for (int fl = 0; fl < 16; ++fl) {
            int f = h * 16 + fl;
            bf16x8 bb = *reinterpret_cast<const bf16x8*>(Bp + f * 32);
            int ul = fl * 4 + lg;
#pragma unroll
            for (int rg = 0; rg < 2; ++rg) {
                int r = rg * 16 + lrow;
                bf16x8 a = *reinterpret_cast<const bf16x8*>(&Alds[(r * 64 + (ul ^ (r & 7))) * 8]);
                acc[rg][f & 1] = mfma16(a, bb, acc[rg][f & 1]);
            }
        }
    }
    int rl = lg * 4;

    if constexpr (!HASW) {
#pragma unroll
        for (int rg = 0; rg < 2; ++rg) {
            f32x4 s = acc[rg][0] + acc[rg][1];
            int rbase = m0 + rg * 16 + rl;
            float4 d4 = *reinterpret_cast<const float4*>(&dinv[rbase]);
            int col = c0 + lrow;
            float bv = bias[col];
            float v0 = fmaxf(s[0] * d4.x + bv, 0.f);
            float v1 = fmaxf(s[1] * d4.y + bv, 0.f);
            float v2 = fmaxf(s[2] * d4.z + bv, 0.f);
            float v3 = fmaxf(s[3] * d4.w + bv, 0.f);
            float* op = outp + (size_t)rbase * GH + col;
            if (MODE == 0) {
                op[0] = 0.25f * v0; op[GH] = 0.25f * v1;
                op[2 * GH] = 0.25f * v2; op[3 * GH] = 0.25f * v3;
            } else {
                op[0] += 0.25f * v0; op[GH] += 0.25f * v1;
                op[2 * GH] += 0.25f * v2; op[3 * GH] += 0.25f * v3;
            }
            if (MODE != 2) {
                bf16x4 h4;
                h4[0] = (bf16)(v0 * d4.x); h4[1] = (bf16)(v1 * d4.y);
                h4[2] = (bf16)(v2 * d4.z); h4[3] = (bf16)(v3 * d4.w);
                *reinterpret_cast<bf16x4*>(Hst + (size_t)col * MROWS + rbase) = h4;
            }
        }
    } else {
        __syncthreads();  // phase separation before T-writes
        {
            int tcol = c0 + lrow;
#pragma unroll
            for (int rg = 0; rg < 2; ++rg) {
                f32x4 s = acc[rg][0] + acc[rg][1];
#pragma unroll
                for (int r = 0; r < 4; ++r) {
                    int trow = rg * 16 + rl + r;
                    float tv = s[r];
                    bf16 hi = (bf16)tv;
                    int ei = trow * 128 + (tcol ^ ((trow & 7) << 3));
                    Ths[ei] = hi;
                    Tls[ei] = (bf16)(tv - (float)hi);
                }
            }
        }
        __syncthreads();
        // U = T@W; wave owns U cols wave*16..+15; K=128; wv reused across both row-groups
        f32x4 u[2] = {};
        int wcol = c0 + lrow;
#pragma unroll
        for (int ks = 0; ks < 4; ++ks) {
            int e0 = ks * 32 + lg * 8;
            bf16x8 wv = *reinterpret_cast<const bf16x8*>(Wt + (size_t)wcol * GH + e0);
#pragma unroll
            for (int rg = 0; rg < 2; ++rg) {
                int trow2 = rg * 16 + lrow;
                int te = trow2 * 128 + (e0 ^ ((trow2 & 7) << 3));
                bf16x8 thi = *reinterpret_cast<const bf16x8*>(&Ths[te]);
                bf16x8 tlo = *reinterpret_cast<const bf16x8*>(&Tls[te]);
                u[rg] = mfma16(thi, wv, u[rg]);
                u[rg] = mfma16(tlo, wv, u[rg]);
            }
        }
#pragma unroll
        for (int rg = 0; rg < 2; ++rg) {
            int rbase = m0 + rg * 16 + rl;
            float4 d4 = *reinterpret_cast<const float4*>(&dinv[rbase]);
            float bv = bias[wcol];
            float v0 = fmaxf(u[rg][0] * d4.x + bv, 0.f);
            float v1 = fmaxf(u[rg][1] * d4.y + bv, 0.f);
            float v2 = fmaxf(u[rg][2] * d4.z + bv, 0.f);
            float v3 = fmaxf(u[rg][3] * d4.w + bv, 0.f);
            float* op = outp + (size_t)rbase * GH + wcol;
            if (MODE == 0) {
                op[0] = 0.25f * v0; op[GH] = 0.25f * v1;
                op[2 * GH] = 0.25f * v2; op[3 * GH] = 0.25f * v3;
            } else {
                op[0] += 0.25f * v0; op[GH] += 0.25f * v1;
                op[2 * GH] += 0.25f * v2; op[3 * GH] += 0.25f * v3;
            }
            if (MODE != 2) {
                bf16x4 h4;
                h4[0] = (bf16)(v0 * d4.x); h4[1] = (bf16)(v1 * d4.y);
                h4[2] = (bf16)(v2 * d4.z); h4[3] = (bf16)(v3 * d4.w);
                *reinterpret_cast<bf16x4*>(Hst + (size_t)wcol * MROWS + rbase) = h4;
            }
        }
    }
}

extern "C" void kernel_launch(void* const* d_in, const int* in_sizes, int n_in,
                              void* d_out, int out_size, void* d_ws, size_t ws_size,
                              hipStream_t stream) {
    const float* aa    = (const float*)d_in[0];
    const int*   rpa   = (const int*)d_in[1];
    const float* W_in  = (const float*)d_in[2];
    const float* b_in  = (const float*)d_in[3];
    const float* W_h0  = (const float*)d_in[4];
    const float* b_h0  = (const float*)d_in[5];
    const float* W_h1  = (const float*)d_in[6];
    const float* b_h1  = (const float*)d_in[7];
    const float* W_out = (const float*)d_in[8];
    const float* b_out = (const float*)d_in[9];
    float* out = (float*)d_out;

    char* ws = (char*)d_ws;
    size_t off = 0;
    float* dinv = (float*)(ws + off); off += (size_t)MROWS * 4;                     // 32KB
    unsigned char* A01b = (unsigned char*)(ws + off); off += (size_t)MROWS * 128;   // 1MB bitmask
    bf16*  Yt   = (bf16*)(ws + off);  off += (size_t)GH * MROWS * 2;                // 2MB
    bf16*  HstA = (bf16*)(ws + off);  off += (size_t)GH * MROWS * 2;                // 2MB
    bf16*  HstB = (bf16*)(ws + off);  off += (size_t)GH * MROWS * 2;                // 2MB
    bf16*  Wt0  = (bf16*)(ws + off);  off += (size_t)GH * NN * 2;                   // 256KB
    bf16*  Wt1  = (bf16*)(ws + off);  off += (size_t)GH * GH * 2;
    bf16*  Wt2  = (bf16*)(ws + off);  off += (size_t)GH * GH * 2;
    bf16*  Wt3  = (bf16*)(ws + off);  off += (size_t)GH * GH * 2;

    wtrans0_kernel<<<64, 256, 0, stream>>>(W_in, Wt0);
    prep_gemm_kernel<<<1280, 512, 0, stream>>>(rpa, aa, W_h0, W_h1, W_out, Wt0,
                                               A01b, dinv, Wt1, Wt2, Wt3, Yt);
    fused3_kernel<0, false, true><<<256, 512, 0, stream>>>(A01b, Yt,   Wt1, dinv, b_in,  HstA, out);
    fused3_kernel<1, true, false><<<256, 512, 0, stream>>>(A01b, HstA, Wt1, dinv, b_h0, HstB, out);
    fused3_kernel<1, true, false><<<256, 512, 0, stream>>>(A01b, HstB, Wt2, dinv, b_h1, HstA, out);
    fused3_kernel<2, true, false><<<256, 512, 0, stream>>>(A01b, HstA, Wt3, dinv, b_out, HstB, out);
}

// Round 18
// 81.806 us; speedup vs baseline: 1.2018x; 1.2018x over previous
//
#include <hip/hip_runtime.h>
#include <hip/hip_bf16.h>

typedef __bf16 bf16;
typedef __bf16 bf16x4 __attribute__((ext_vector_type(4)));
typedef __bf16 bf16x8 __attribute__((ext_vector_type(8)));
typedef float f32x4 __attribute__((ext_vector_type(4)));

#define NN 1024
#define GH 128
#define MROWS 8192  // 8*1024

static __device__ __forceinline__ f32x4 mfma16(bf16x8 a, bf16x8 b, f32x4 c) {
    return __builtin_amdgcn_mfma_f32_16x16x32_bf16(a, b, c, 0, 0, 0);
}

// ---------------- prep: A as 1-bit mask (diag=1) + dinv; wtrans folded (R13/R14, verified) ----------------
__global__ __launch_bounds__(256) void prep_kernel(
        const int* __restrict__ rpa,
        const float* __restrict__ W0, const float* __restrict__ W1,
        const float* __restrict__ W2, const float* __restrict__ W3,
        unsigned char* __restrict__ A01b, float* __restrict__ dinv,
        bf16* __restrict__ T0, bf16* __restrict__ T1,
        bf16* __restrict__ T2, bf16* __restrict__ T3) {
    int bid = blockIdx.x;
    {
        int rb = (bid & 7) * 256 + (bid >> 3);  // XCD-local batch
        int row  = rb * 4 + (threadIdx.x >> 6);
        int lane = threadIdx.x & 63;
        int i = row & (NN - 1);
        const int4* p = reinterpret_cast<const int4*>(rpa + (size_t)row * NN);
        unsigned char* brow = A01b + (size_t)row * 128;
        int cnt = 0;
#pragma unroll
        for (int it = 0; it < 4; ++it) {
            int4 v = p[lane + it * 64];
            int j = (lane + it * 64) * 4;
            int a0 = (v.x != 0), a1 = (v.y != 0), a2 = (v.z != 0), a3 = (v.w != 0);
            cnt += (a0 & (j + 0 != i)) + (a1 & (j + 1 != i)) +
                   (a2 & (j + 2 != i)) + (a3 & (j + 3 != i));
            unsigned nib = (unsigned)(a0 | (j + 0 == i))
                         | ((unsigned)(a1 | (j + 1 == i)) << 1)
                         | ((unsigned)(a2 | (j + 2 == i)) << 2)
                         | ((unsigned)(a3 | (j + 3 == i)) << 3);
            unsigned pn = __shfl_xor(nib, 1, 64);
            if (!(lane & 1))
                brow[it * 32 + (lane >> 1)] = (unsigned char)(nib | (pn << 4));
        }
#pragma unroll
        for (int off = 32; off > 0; off >>= 1) cnt += __shfl_down(cnt, off, 64);
        if (lane == 0) dinv[row] = rsqrtf((float)(cnt + 1));  // +1 self-loop
    }
    if (threadIdx.x < 11) {
        int t = bid * 11 + threadIdx.x;  // 0..22527
        const float* W; bf16* T; int K; int local;
        if (t < 16384)      { W = W0; T = T0; K = NN; local = t; }
        else if (t < 18432) { W = W1; T = T1; K = GH; local = t - 16384; }
        else if (t < 20480) { W = W2; T = T2; K = GH; local = t - 18432; }
        else                { W = W3; T = T3; K = GH; local = t - 20480; }
        int n = local & 127, k0 = (local >> 7) * 8;
        bf16x8 o;
#pragma unroll
        for (int ii = 0; ii < 8; ++ii) o[ii] = (bf16)W[(size_t)(k0 + ii) * GH + n];
        *reinterpret_cast<bf16x8*>(T + (size_t)n * K + k0) = o;
    }
}

// ---------------- gemm3: Xt = (D * aa @ Wt0)^T ; M=32 tile; A staged per K-HALF (32KB LDS) ----------------
// grid 256 x 512 thr; 4 blocks/CU (was 2 at 64KB). MFMA order identical to R14.
__global__ __launch_bounds__(512, 4) void gemm3_kernel(const float* __restrict__ aa,
                                                       const bf16* __restrict__ Wt,
                                                       const float* __restrict__ dinv,
                                                       bf16* __restrict__ Zt) {
    __shared__ bf16 Alds[16384];  // 32KB: [32 rows][64 units] (one K-half); unit u at u^(row&7)
    int tid = threadIdx.x;
    int wave = tid >> 6, lane = tid & 63;
    int lrow = lane & 15, lg = lane >> 4;
    int lb = (blockIdx.x & 7) * 32 + (blockIdx.x >> 3);  // bijective; batch = bid%8 = XCD
    int m0 = lb * 32;
    int c0 = wave * 16;
    const bf16* Bp = Wt + (size_t)(c0 + lrow) * NN + lg * 8;
    f32x4 acc[2][2] = {};
    int arow = tid >> 4;            // staging: row 0..31
    int au   = (tid & 15) * 4;      // 4 units (of 8 f32) per thread per half
    int ars  = arow & 7;
#pragma unroll
    for (int h = 0; h < 2; ++h) {
        if (h) __syncthreads();     // WAR: previous-half A-reads done
        {
            const float* src = aa + (size_t)(m0 + arow) * NN + h * 512 + au * 8;
#pragma unroll
            for (int i = 0; i < 4; ++i) {
                float4 f0 = *reinterpret_cast<const float4*>(src + i * 8);
                float4 f1 = *reinterpret_cast<const float4*>(src + i * 8 + 4);
                bf16x8 v;
                v[0] = (bf16)f0.x; v[1] = (bf16)f0.y; v[2] = (bf16)f0.z; v[3] = (bf16)f0.w;
                v[4] = (bf16)f1.x; v[5] = (bf16)f1.y; v[6] = (bf16)f1.z; v[7] = (bf16)f1.w;
                *reinterpret_cast<bf16x8*>(&Alds[(arow * 64 + ((au + i) ^ ars)) * 8]) = v;
            }
        }
        __syncthreads();
#pragma unroll
        for (int fl = 0; fl < 16; ++fl) {
            int f = h * 16 + fl;
            bf16x8 bb = *reinterpret_cast<const bf16x8*>(Bp + f * 32);
            int ul = fl * 4 + lg;
#pragma unroll
            for (int rg = 0; rg < 2; ++rg) {
                int r = rg * 16 + lrow;
                bf16x8 a = *reinterpret_cast<const bf16x8*>(&Alds[(r * 64 + (ul ^ (r & 7))) * 8]);
                acc[rg][f & 1] = mfma16(a, bb, acc[rg][f & 1]);
            }
        }
    }
    int rl = lg * 4;
    int col = c0 + lrow;
#pragma unroll
    for (int rg = 0; rg < 2; ++rg) {
        f32x4 s = acc[rg][0] + acc[rg][1];
        int rbase = m0 + rg * 16 + rl;
        float4 d4 = *reinterpret_cast<const float4*>(&dinv[rbase]);
        bf16x4 o;
        o[0] = (bf16)(s[0] * d4.x);
        o[1] = (bf16)(s[1] * d4.y);
        o[2] = (bf16)(s[2] * d4.z);
        o[3] = (bf16)(s[3] * d4.w);
        *reinterpret_cast<bf16x4*>(Zt + (size_t)col * MROWS + rbase) = o;
    }
}

// ---------------- fused3: T = A01_b @ Xt_b ; [U=T@W] ; v = relu(D*U+b) ; M=32, K-QUARTER A ----------------
// Alds 16KB (was 32KB) -> total LDS 32KB -> 4 blocks/CU (was 3). MFMA order identical to R14.
// Dedicated Ths/Tls (R10 race lesson: never alias LDS across MFMA phases).
template <int MODE, bool HASW>
__global__ __launch_bounds__(512, 4) void fused3_kernel(const unsigned char* __restrict__ A01b,
                                                        const bf16* __restrict__ Xt,
                                                        const bf16* __restrict__ Wt,
                                                        const float* __restrict__ dinv,
                                                        const float* __restrict__ bias,
                                                        bf16* __restrict__ Hst,
                                                        float* __restrict__ outp) {
    __shared__ bf16 Alds[8192];   // 16KB: [32 rows][32 units] (one K-quarter)
    __shared__ bf16 Ths[4096];    // 8KB: 32x128 T hi (dedicated)
    __shared__ bf16 Tls[4096];    // 8KB: T lo
    int tid = threadIdx.x;
    int wave = tid >> 6, lane = tid & 63;
    int lrow = lane & 15, lg = lane >> 4;
    int lb = (blockIdx.x & 7) * 32 + (blockIdx.x >> 3);
    int m0 = lb * 32;
    int b = blockIdx.x & 7;
    int c0 = wave * 16;
    const bf16* Bp = Xt + (size_t)(c0 + lrow) * MROWS + b * NN + lg * 8;
    f32x4 acc[2][2] = {};
    int erow = tid >> 4;                 // expansion: thread's row (0..31)
    int eb2  = (tid & 15) * 2;           // 2 units (bytes) per thread per quarter
    int ers  = erow & 7;
#pragma unroll
    for (int h = 0; h < 4; ++h) {
        if (h) __syncthreads();          // WAR: previous-quarter A-reads done before overwrite
        {
            unsigned short w = *reinterpret_cast<const unsigned short*>(
                A01b + (size_t)(m0 + erow) * 128 + h * 32 + eb2);
#pragma unroll
            for (int i = 0; i < 2; ++i) {
                unsigned byte = (w >> (8 * i)) & 0xffu;
                bf16x8 v;
#pragma unroll
                for (int k = 0; k < 8; ++k) v[k] = ((byte >> k) & 1u) ? (bf16)1.f : (bf16)0.f;
                *reinterpret_cast<bf16x8*>(&Alds[(erow * 32 + ((eb2 + i) ^ ers)) * 8]) = v;
            }
        }
        __syncthreads();
#pragma unroll
        for (int fl = 0; fl < 8; ++fl) {
            int f = h * 8 + fl;
            bf16x8 bb = *reinterpret_cast<const bf16x8*>(Bp + f * 32);
            int ul = fl * 4 + lg;
#pragma unroll
            for (int rg = 0; rg < 2; ++rg) {
                int r = rg * 16 + lrow;
                bf16x8 a = *reinterpret_cast<const bf16x8*>(&Alds[(r * 32 + (ul ^ (r & 7))) * 8]);
                acc[rg][f & 1] = mfma16(a, bb, acc[rg][f & 1]);
            }
        }
    }
    int rl = lg * 4;

    if constexpr (!HASW) {
#pragma unroll
        for (int rg = 0; rg < 2; ++rg) {
            f32x4 s = acc[rg][0] + acc[rg][1];
            int rbase = m0 + rg * 16 + rl;
            float4 d4 = *reinterpret_cast<const float4*>(&dinv[rbase]);
            int col = c0 + lrow;
            float bv = bias[col];
            float v0 = fmaxf(s[0] * d4.x + bv, 0.f);
            float v1 = fmaxf(s[1] * d4.y + bv, 0.f);
            float v2 = fmaxf(s[2] * d4.z + bv, 0.f);
            float v3 = fmaxf(s[3] * d4.w + bv, 0.f);
            float* op = outp + (size_t)rbase * GH + col;
            if (MODE == 0) {
                op[0] = 0.25f * v0; op[GH] = 0.25f * v1;
                op[2 * GH] = 0.25f * v2; op[3 * GH] = 0.25f * v3;
            } else {
                op[0] += 0.25f * v0; op[GH] += 0.25f * v1;
                op[2 * GH] += 0.25f * v2; op[3 * GH] += 0.25f * v3;
            }
            if (MODE != 2) {
                bf16x4 h4;
                h4[0] = (bf16)(v0 * d4.x); h4[1] = (bf16)(v1 * d4.y);
                h4[2] = (bf16)(v2 * d4.z); h4[3] = (bf16)(v3 * d4.w);
                *reinterpret_cast<bf16x4*>(Hst + (size_t)col * MROWS + rbase) = h4;
            }
        }
    } else {
        __syncthreads();  // phase separation before T-writes
        {
            int tcol = c0 + lrow;
#pragma unroll
            for (int rg = 0; rg < 2; ++rg) {
                f32x4 s = acc[rg][0] + acc[rg][1];
#pragma unroll
                for (int r = 0; r < 4; ++r) {
                    int trow = rg * 16 + rl + r;
                    float tv = s[r];
                    bf16 hi = (bf16)tv;
                    int ei = trow * 128 + (tcol ^ ((trow & 7) << 3));
                    Ths[ei] = hi;
                    Tls[ei] = (bf16)(tv - (float)hi);
                }
            }
        }
        __syncthreads();
        // U = T@W; wave owns U cols wave*16..+15; K=128; wv reused across both row-groups
        f32x4 u[2] = {};
        int wcol = c0 + lrow;
#pragma unroll
        for (int ks = 0; ks < 4; ++ks) {
            int e0 = ks * 32 + lg * 8;
            bf16x8 wv = *reinterpret_cast<const bf16x8*>(Wt + (size_t)wcol * GH + e0);
#pragma unroll
            for (int rg = 0; rg < 2; ++rg) {
                int trow2 = rg * 16 + lrow;
                int te = trow2 * 128 + (e0 ^ ((trow2 & 7) << 3));
                bf16x8 thi = *reinterpret_cast<const bf16x8*>(&Ths[te]);
                bf16x8 tlo = *reinterpret_cast<const bf16x8*>(&Tls[te]);
                u[rg] = mfma16(thi, wv, u[rg]);
                u[rg] = mfma16(tlo, wv, u[rg]);
            }
        }
#pragma unroll
        for (int rg = 0; rg < 2; ++rg) {
            int rbase = m0 + rg * 16 + rl;
            float4 d4 = *reinterpret_cast<const float4*>(&dinv[rbase]);
            float bv = bias[wcol];
            float v0 = fmaxf(u[rg][0] * d4.x + bv, 0.f);
            float v1 = fmaxf(u[rg][1] * d4.y + bv, 0.f);
            float v2 = fmaxf(u[rg][2] * d4.z + bv, 0.f);
            float v3 = fmaxf(u[rg][3] * d4.w + bv, 0.f);
            float* op = outp + (size_t)rbase * GH + wcol;
            if (MODE == 0) {
                op[0] = 0.25f * v0; op[GH] = 0.25f * v1;
                op[2 * GH] = 0.25f * v2; op[3 * GH] = 0.25f * v3;
            } else {
                op[0] += 0.25f * v0; op[GH] += 0.25f * v1;
                op[2 * GH] += 0.25f * v2; op[3 * GH] += 0.25f * v3;
            }
            if (MODE != 2) {
                bf16x4 h4;
                h4[0] = (bf16)(v0 * d4.x); h4[1] = (bf16)(v1 * d4.y);
                h4[2] = (bf16)(v2 * d4.z); h4[3] = (bf16)(v3 * d4.w);
                *reinterpret_cast<bf16x4*>(Hst + (size_t)wcol * MROWS + rbase) = h4;
            }
        }
    }
}

extern "C" void kernel_launch(void* const* d_in, const int* in_sizes, int n_in,
                              void* d_out, int out_size, void* d_ws, size_t ws_size,
                              hipStream_t stream) {
    const float* aa    = (const float*)d_in[0];
    const int*   rpa   = (const int*)d_in[1];
    const float* W_in  = (const float*)d_in[2];
    const float* b_in  = (const float*)d_in[3];
    const float* W_h0  = (const float*)d_in[4];
    const float* b_h0  = (const float*)d_in[5];
    const float* W_h1  = (const float*)d_in[6];
    const float* b_h1  = (const float*)d_in[7];
    const float* W_out = (const float*)d_in[8];
    const float* b_out = (const float*)d_in[9];
    float* out = (float*)d_out;

    char* ws = (char*)d_ws;
    size_t off = 0;
    float* dinv = (float*)(ws + off); off += (size_t)MROWS * 4;                     // 32KB
    unsigned char* A01b = (unsigned char*)(ws + off); off += (size_t)MROWS * 128;   // 1MB bitmask
    bf16*  Xt   = (bf16*)(ws + off);  off += (size_t)GH * MROWS * 2;                // 2MB
    bf16*  HstA = (bf16*)(ws + off);  off += (size_t)GH * MROWS * 2;                // 2MB
    bf16*  HstB = (bf16*)(ws + off);  off += (size_t)GH * MROWS * 2;                // 2MB
    bf16*  Wt0  = (bf16*)(ws + off);  off += (size_t)GH * NN * 2;                   // 256KB
    bf16*  Wt1  = (bf16*)(ws + off);  off += (size_t)GH * GH * 2;
    bf16*  Wt2  = (bf16*)(ws + off);  off += (size_t)GH * GH * 2;
    bf16*  Wt3  = (bf16*)(ws + off);  off += (size_t)GH * GH * 2;

    prep_kernel<<<2048, 256, 0, stream>>>(rpa, W_in, W_h0, W_h1, W_out,
                                          A01b, dinv, Wt0, Wt1, Wt2, Wt3);
    gemm3_kernel<<<256, 512, 0, stream>>>(aa, Wt0, dinv, Xt);
    fused3_kernel<0, false><<<256, 512, 0, stream>>>(A01b, Xt,   Wt1, dinv, b_in,  HstA, out);
    fused3_kernel<1, true><<<256, 512, 0, stream>>>(A01b, HstA, Wt1, dinv, b_h0, HstB, out);
    fused3_kernel<1, true><<<256, 512, 0, stream>>>(A01b, HstB, Wt2, dinv, b_h1, HstA, out);
    fused3_kernel<2, true><<<256, 512, 0, stream>>>(A01b, HstA, Wt3, dinv, b_out, HstB, out);
}

// Round 19
// 75.585 us; speedup vs baseline: 1.3007x; 1.0823x over previous
//
#include <hip/hip_runtime.h>
#include <hip/hip_bf16.h>

typedef __bf16 bf16;
typedef __bf16 bf16x4 __attribute__((ext_vector_type(4)));
typedef __bf16 bf16x8 __attribute__((ext_vector_type(8)));
typedef float f32x4 __attribute__((ext_vector_type(4)));

#define NN 1024
#define GH 128
#define MROWS 8192  // 8*1024

static __device__ __forceinline__ f32x4 mfma16(bf16x8 a, bf16x8 b, f32x4 c) {
    return __builtin_amdgcn_mfma_f32_16x16x32_bf16(a, b, c, 0, 0, 0);
}

// ---------------- prep: A as 1-bit mask (diag=1) + dinv; wtrans folded (R13, verified) ----------------
__global__ __launch_bounds__(256) void prep_kernel(
        const int* __restrict__ rpa,
        const float* __restrict__ W0, const float* __restrict__ W1,
        const float* __restrict__ W2, const float* __restrict__ W3,
        unsigned char* __restrict__ A01b, float* __restrict__ dinv,
        bf16* __restrict__ T0, bf16* __restrict__ T1,
        bf16* __restrict__ T2, bf16* __restrict__ T3) {
    int bid = blockIdx.x;
    {
        int rb = (bid & 7) * 256 + (bid >> 3);  // XCD-local batch
        int row  = rb * 4 + (threadIdx.x >> 6);
        int lane = threadIdx.x & 63;
        int i = row & (NN - 1);
        const int4* p = reinterpret_cast<const int4*>(rpa + (size_t)row * NN);
        unsigned char* brow = A01b + (size_t)row * 128;
        int cnt = 0;
#pragma unroll
        for (int it = 0; it < 4; ++it) {
            int4 v = p[lane + it * 64];
            int j = (lane + it * 64) * 4;
            int a0 = (v.x != 0), a1 = (v.y != 0), a2 = (v.z != 0), a3 = (v.w != 0);
            cnt += (a0 & (j + 0 != i)) + (a1 & (j + 1 != i)) +
                   (a2 & (j + 2 != i)) + (a3 & (j + 3 != i));
            unsigned nib = (unsigned)(a0 | (j + 0 == i))
                         | ((unsigned)(a1 | (j + 1 == i)) << 1)
                         | ((unsigned)(a2 | (j + 2 == i)) << 2)
                         | ((unsigned)(a3 | (j + 3 == i)) << 3);
            unsigned pn = __shfl_xor(nib, 1, 64);
            if (!(lane & 1))
                brow[it * 32 + (lane >> 1)] = (unsigned char)(nib | (pn << 4));
        }
#pragma unroll
        for (int off = 32; off > 0; off >>= 1) cnt += __shfl_down(cnt, off, 64);
        if (lane == 0) dinv[row] = rsqrtf((float)(cnt + 1));  // +1 self-loop
    }
    if (threadIdx.x < 11) {
        int t = bid * 11 + threadIdx.x;  // 0..22527
        const float* W; bf16* T; int K; int local;
        if (t < 16384)      { W = W0; T = T0; K = NN; local = t; }
        else if (t < 18432) { W = W1; T = T1; K = GH; local = t - 16384; }
        else if (t < 20480) { W = W2; T = T2; K = GH; local = t - 18432; }
        else                { W = W3; T = T3; K = GH; local = t - 20480; }
        int n = local & 127, k0 = (local >> 7) * 8;
        bf16x8 o;
#pragma unroll
        for (int ii = 0; ii < 8; ++ii) o[ii] = (bf16)W[(size_t)(k0 + ii) * GH + n];
        *reinterpret_cast<bf16x8*>(T + (size_t)n * K + k0) = o;
    }
}

// ---------------- gemm3: Xt = (D * aa @ Wt0)^T ; M=32 tile, 2 row-groups per B-frag ----------------
// grid 256 x 512 thr; A (f32->bf16) staged in 64KB swizzled LDS; per f: 1 B-load + 2 MFMA.
__global__ __launch_bounds__(512, 4) void gemm3_kernel(const float* __restrict__ aa,
                                                       const bf16* __restrict__ Wt,
                                                       const float* __restrict__ dinv,
                                                       bf16* __restrict__ Zt) {
    __shared__ bf16 Alds[32768];  // 64KB: [32 rows][128 units]; unit u at u^(row&7)
    int tid = threadIdx.x;
    int wave = tid >> 6, lane = tid & 63;
    int lrow = lane & 15, lg = lane >> 4;
    int lb = (blockIdx.x & 7) * 32 + (blockIdx.x >> 3);  // bijective; batch = bid%8 = XCD
    int m0 = lb * 32;
#pragma unroll
    for (int i = 0; i < 8; ++i) {
        int idx = i * 512 + tid;
        int row = idx >> 7, u = idx & 127;
        const float* src = aa + (size_t)(m0 + row) * NN + u * 8;
        float4 f0 = *reinterpret_cast<const float4*>(src);
        float4 f1 = *reinterpret_cast<const float4*>(src + 4);
        bf16x8 v;
        v[0] = (bf16)f0.x; v[1] = (bf16)f0.y; v[2] = (bf16)f0.z; v[3] = (bf16)f0.w;
        v[4] = (bf16)f1.x; v[5] = (bf16)f1.y; v[6] = (bf16)f1.z; v[7] = (bf16)f1.w;
        *reinterpret_cast<bf16x8*>(&Alds[(row * 128 + (u ^ (row & 7))) * 8]) = v;
    }
    __syncthreads();
    int c0 = wave * 16;
    const bf16* Bp = Wt + (size_t)(c0 + lrow) * NN + lg * 8;
    f32x4 acc[2][2] = {};
#pragma unroll
    for (int f = 0; f < 32; ++f) {
        bf16x8 bb = *reinterpret_cast<const bf16x8*>(Bp + f * 32);
        int u = f * 4 + lg;
#pragma unroll
        for (int rg = 0; rg < 2; ++rg) {
            int r = rg * 16 + lrow;
            bf16x8 a = *reinterpret_cast<const bf16x8*>(&Alds[(r * 128 + (u ^ (r & 7))) * 8]);
            acc[rg][f & 1] = mfma16(a, bb, acc[rg][f & 1]);
        }
    }
    int rl = lg * 4;
    int col = c0 + lrow;
#pragma unroll
    for (int rg = 0; rg < 2; ++rg) {
        f32x4 s = acc[rg][0] + acc[rg][1];
        int rbase = m0 + rg * 16 + rl;
        float4 d4 = *reinterpret_cast<const float4*>(&dinv[rbase]);
        bf16x4 o;
        o[0] = (bf16)(s[0] * d4.x);
        o[1] = (bf16)(s[1] * d4.y);
        o[2] = (bf16)(s[2] * d4.z);
        o[3] = (bf16)(s[3] * d4.w);
        *reinterpret_cast<bf16x4*>(Zt + (size_t)col * MROWS + rbase) = o;
    }
}

// ---------------- fused3: T = A01_b @ Xt_b ; [U=T@W] ; v = relu(D*U+b) ; M=32, K-halved A ----------------
// grid 256 x 512 thr. A expanded from bits per K-half (32KB live) + dedicated Ths/Tls (R10 lesson).
template <int MODE, bool HASW>
__global__ __launch_bounds__(512, 4) void fused3_kernel(const unsigned char* __restrict__ A01b,
                                                        const bf16* __restrict__ Xt,
                                                        const bf16* __restrict__ Wt,
                                                        const float* __restrict__ dinv,
                                                        const float* __restrict__ bias,
                                                        bf16* __restrict__ Hst,
                                                        float* __restrict__ outp) {
    __shared__ bf16 Alds[16384];  // 32KB: [32 rows][64 units] (one K-half)
    __shared__ bf16 Ths[4096];    // 8KB: 32x128 T hi (dedicated)
    __shared__ bf16 Tls[4096];    // 8KB: T lo
    int tid = threadIdx.x;
    int wave = tid >> 6, lane = tid & 63;
    int lrow = lane & 15, lg = lane >> 4;
    int lb = (blockIdx.x & 7) * 32 + (blockIdx.x >> 3);
    int m0 = lb * 32;
    int b = blockIdx.x & 7;
    int c0 = wave * 16;
    const bf16* Bp = Xt + (size_t)(c0 + lrow) * MROWS + b * NN + lg * 8;
    f32x4 acc[2][2] = {};
    int erow = tid >> 4;                 // expansion: thread's row (0..31)
    int eub  = (tid & 15) * 4;           // 4 units (bytes) per thread per half
    int ers  = erow & 7;
#pragma unroll
    for (int h = 0; h < 2; ++h) {
        if (h) __syncthreads();          // WAR: all half-0 A-reads done before overwrite
        {
            unsigned w = *reinterpret_cast<const unsigned*>(
                A01b + (size_t)(m0 + erow) * 128 + h * 64 + eub);
#pragma unroll
            for (int i = 0; i < 4; ++i) {
                unsigned byte = (w >> (8 * i)) & 0xffu;
                bf16x8 v;
#pragma unroll
                for (int k = 0; k < 8; ++k) v[k] = ((byte >> k) & 1u) ? (bf16)1.f : (bf16)0.f;
                *reinterpret_cast<bf16x8*>(&Alds[(erow * 64 + ((eub + i) ^ ers)) * 8]) = v;
            }
        }
        __syncthreads();
#pragma unroll
        for (int fl = 0; fl < 16; ++fl) {
            int f = h * 16 + fl;
            bf16x8 bb = *reinterpret_cast<const bf16x8*>(Bp + f * 32);
            int ul = fl * 4 + lg;
#pragma unroll
            for (int rg = 0; rg < 2; ++rg) {
                int r = rg * 16 + lrow;
                bf16x8 a = *reinterpret_cast<const bf16x8*>(&Alds[(r * 64 + (ul ^ (r & 7))) * 8]);
                acc[rg][f & 1] = mfma16(a, bb, acc[rg][f & 1]);
            }
        }
    }
    int rl = lg * 4;

    if constexpr (!HASW) {
#pragma unroll
        for (int rg = 0; rg < 2; ++rg) {
            f32x4 s = acc[rg][0] + acc[rg][1];
            int rbase = m0 + rg * 16 + rl;
            float4 d4 = *reinterpret_cast<const float4*>(&dinv[rbase]);
            int col = c0 + lrow;
            float bv = bias[col];
            float v0 = fmaxf(s[0] * d4.x + bv, 0.f);
            float v1 = fmaxf(s[1] * d4.y + bv, 0.f);
            float v2 = fmaxf(s[2] * d4.z + bv, 0.f);
            float v3 = fmaxf(s[3] * d4.w + bv, 0.f);
            float* op = outp + (size_t)rbase * GH + col;
            if (MODE == 0) {
                op[0] = 0.25f * v0; op[GH] = 0.25f * v1;
                op[2 * GH] = 0.25f * v2; op[3 * GH] = 0.25f * v3;
            } else {
                op[0] += 0.25f * v0; op[GH] += 0.25f * v1;
                op[2 * GH] += 0.25f * v2; op[3 * GH] += 0.25f * v3;
            }
            if (MODE != 2) {
                bf16x4 h4;
                h4[0] = (bf16)(v0 * d4.x); h4[1] = (bf16)(v1 * d4.y);
                h4[2] = (bf16)(v2 * d4.z); h4[3] = (bf16)(v3 * d4.w);
                *reinterpret_cast<bf16x4*>(Hst + (size_t)col * MROWS + rbase) = h4;
            }
        }
    } else {
        __syncthreads();  // phase separation before T-writes
        {
            int tcol = c0 + lrow;
#pragma unroll
            for (int rg = 0; rg < 2; ++rg) {
                f32x4 s = acc[rg][0] + acc[rg][1];
#pragma unroll
                for (int r = 0; r < 4; ++r) {
                    int trow = rg * 16 + rl + r;
                    float tv = s[r];
                    bf16 hi = (bf16)tv;
                    int ei = trow * 128 + (tcol ^ ((trow & 7) << 3));
                    Ths[ei] = hi;
                    Tls[ei] = (bf16)(tv - (float)hi);
                }
            }
        }
        __syncthreads();
        // U = T@W; wave owns U cols wave*16..+15; K=128; wv reused across both row-groups
        f32x4 u[2] = {};
        int wcol = c0 + lrow;
#pragma unroll
        for (int ks = 0; ks < 4; ++ks) {
            int e0 = ks * 32 + lg * 8;
            bf16x8 wv = *reinterpret_cast<const bf16x8*>(Wt + (size_t)wcol * GH + e0);
#pragma unroll
            for (int rg = 0; rg < 2; ++rg) {
                int trow2 = rg * 16 + lrow;
                int te = trow2 * 128 + (e0 ^ ((trow2 & 7) << 3));
                bf16x8 thi = *reinterpret_cast<const bf16x8*>(&Ths[te]);
                bf16x8 tlo = *reinterpret_cast<const bf16x8*>(&Tls[te]);
                u[rg] = mfma16(thi, wv, u[rg]);
                u[rg] = mfma16(tlo, wv, u[rg]);
            }
        }
#pragma unroll
        for (int rg = 0; rg < 2; ++rg) {
            int rbase = m0 + rg * 16 + rl;
            float4 d4 = *reinterpret_cast<const float4*>(&dinv[rbase]);
            float bv = bias[wcol];
            float v0 = fmaxf(u[rg][0] * d4.x + bv, 0.f);
            float v1 = fmaxf(u[rg][1] * d4.y + bv, 0.f);
            float v2 = fmaxf(u[rg][2] * d4.z + bv, 0.f);
            float v3 = fmaxf(u[rg][3] * d4.w + bv, 0.f);
            float* op = outp + (size_t)rbase * GH + wcol;
            if (MODE == 0) {
                op[0] = 0.25f * v0; op[GH] = 0.25f * v1;
                op[2 * GH] = 0.25f * v2; op[3 * GH] = 0.25f * v3;
            } else {
                op[0] += 0.25f * v0; op[GH] += 0.25f * v1;
                op[2 * GH] += 0.25f * v2; op[3 * GH] += 0.25f * v3;
            }
            if (MODE != 2) {
                bf16x4 h4;
                h4[0] = (bf16)(v0 * d4.x); h4[1] = (bf16)(v1 * d4.y);
                h4[2] = (bf16)(v2 * d4.z); h4[3] = (bf16)(v3 * d4.w);
                *reinterpret_cast<bf16x4*>(Hst + (size_t)wcol * MROWS + rbase) = h4;
            }
        }
    }
}

extern "C" void kernel_launch(void* const* d_in, const int* in_sizes, int n_in,
                              void* d_out, int out_size, void* d_ws, size_t ws_size,
                              hipStream_t stream) {
    const float* aa    = (const float*)d_in[0];
    const int*   rpa   = (const int*)d_in[1];
    const float* W_in  = (const float*)d_in[2];
    const float* b_in  = (const float*)d_in[3];
    const float* W_h0  = (const float*)d_in[4];
    const float* b_h0  = (const float*)d_in[5];
    const float* W_h1  = (const float*)d_in[6];
    const float* b_h1  = (const float*)d_in[7];
    const float* W_out = (const float*)d_in[8];
    const float* b_out = (const float*)d_in[9];
    float* out = (float*)d_out;

    char* ws = (char*)d_ws;
    size_t off = 0;
    float* dinv = (float*)(ws + off); off += (size_t)MROWS * 4;                     // 32KB
    unsigned char* A01b = (unsigned char*)(ws + off); off += (size_t)MROWS * 128;   // 1MB bitmask
    bf16*  Xt   = (bf16*)(ws + off);  off += (size_t)GH * MROWS * 2;                // 2MB
    bf16*  HstA = (bf16*)(ws + off);  off += (size_t)GH * MROWS * 2;                // 2MB
    bf16*  HstB = (bf16*)(ws + off);  off += (size_t)GH * MROWS * 2;                // 2MB
    bf16*  Wt0  = (bf16*)(ws + off);  off += (size_t)GH * NN * 2;                   // 256KB
    bf16*  Wt1  = (bf16*)(ws + off);  off += (size_t)GH * GH * 2;
    bf16*  Wt2  = (bf16*)(ws + off);  off += (size_t)GH * GH * 2;
    bf16*  Wt3  = (bf16*)(ws + off);  off += (size_t)GH * GH * 2;

    prep_kernel<<<2048, 256, 0, stream>>>(rpa, W_in, W_h0, W_h1, W_out,
                                          A01b, dinv, Wt0, Wt1, Wt2, Wt3);
    gemm3_kernel<<<256, 512, 0, stream>>>(aa, Wt0, dinv, Xt);
    fused3_kernel<0, false><<<256, 512, 0, stream>>>(A01b, Xt,   Wt1, dinv, b_in,  HstA, out);
    fused3_kernel<1, true><<<256, 512, 0, stream>>>(A01b, HstA, Wt1, dinv, b_h0, HstB, out);
    fused3_kernel<1, true><<<256, 512, 0, stream>>>(A01b, HstB, Wt2, dinv, b_h1, HstA, out);
    fused3_kernel<2, true><<<256, 512, 0, stream>>>(A01b, HstA, Wt3, dinv, b_out, HstB, out);
}